// Round 9
// baseline (1446.996 us; speedup 1.0000x reference)
//
#include <hip/hip_runtime.h>

#define MROWS 32
#define FILLK 8
#define WCHUNK 4096

typedef __attribute__((ext_vector_type(8))) short short8v;   // 8 bf16 = 4 VGPR
typedef __attribute__((ext_vector_type(4))) float f32x4;

__device__ __forceinline__ unsigned short f2bf(float f) {
  unsigned u = __builtin_bit_cast(unsigned, f);
  unsigned r = (u + 0x7fffu + ((u >> 16) & 1u)) >> 16;   // RNE
  return (unsigned short)r;
}
__device__ __forceinline__ float bf2f(unsigned short s) {
  return __builtin_bit_cast(float, (unsigned)s << 16);
}

// ---------------- prep: zero zn ints + x->bf16 + weight repack ----------------
__global__ __launch_bounds__(256) void prep_kernel(
    const float* __restrict__ x, const float* __restrict__ W1,
    const float* __restrict__ W2, int* __restrict__ zp,
    unsigned short* __restrict__ xb, short* __restrict__ w1p,
    short* __restrict__ w2p, int N, int zn) {
  const int Z = zn;
  const int X = 16 * N;
  const int grand = Z + X + 131072;
  int i = blockIdx.x * blockDim.x + threadIdx.x;
  int stride = gridDim.x * blockDim.x;
  for (; i < grand; i += stride) {
    if (i < Z) {
      zp[i] = 0;
    } else if (i < Z + X) {
      int t = i - Z;
      const float4* p = (const float4*)(x + (size_t)t * 8);
      float4 q0 = p[0], q1 = p[1];
      short8v s;
      s[0] = (short)f2bf(q0.x); s[1] = (short)f2bf(q0.y);
      s[2] = (short)f2bf(q0.z); s[3] = (short)f2bf(q0.w);
      s[4] = (short)f2bf(q1.x); s[5] = (short)f2bf(q1.y);
      s[6] = (short)f2bf(q1.z); s[7] = (short)f2bf(q1.w);
      *(short8v*)(xb + (size_t)t * 8) = s;
    } else {
      int t = i - Z - X;          // 0..131071
      int idx = t & 65535;
      int frag = idx >> 9, rem = idx & 511;
      int lane = rem >> 3, j = rem & 7;
      if (t < 65536) {
        int nt = frag >> 2, ks = frag & 3;
        int k = ks * 32 + (lane >> 4) * 8 + j;
        int c = nt * 16 + (lane & 15);
        w1p[idx] = (short)f2bf(W1[k * 512 + c]);
      } else {
        int nt = frag >> 4, ks = frag & 15;
        int k = ks * 32 + (lane >> 4) * 8 + j;
        int c = nt * 16 + (lane & 15);
        w2p[idx] = (short)f2bf(W2[k * 128 + c]);
      }
    }
  }
}

// ================= bucket path (N <= 65536) =================
// bucket b = node >> 7 (128 nodes per bucket)

__global__ __launch_bounds__(256) void bcount_kernel(const int* __restrict__ ei,
    int* __restrict__ bcount, int total, int NB) {
  __shared__ int hist[512];
  for (int i = threadIdx.x; i < 512; i += 256) hist[i] = 0;
  __syncthreads();
  int i = blockIdx.x * blockDim.x + threadIdx.x;
  int stride = gridDim.x * blockDim.x;
  for (; i < total; i += stride) atomicAdd(&hist[((unsigned)ei[i]) >> 7], 1);
  __syncthreads();
  for (int b = threadIdx.x; b < NB; b += 256)
    if (hist[b]) atomicAdd(&bcount[b], hist[b]);   // non-returning: fast
}

// single-wave exclusive scan over NB buckets -> boffs[0..NB], gcursor[b]=boffs[b]
__global__ __launch_bounds__(64) void scan_cur_kernel(const int* __restrict__ bcount,
    int* __restrict__ boffs, int* __restrict__ gcursor, int n) {
  int lane = threadIdx.x;
  int carry = 0;
  if (lane == 0) boffs[0] = 0;
  for (int base = 0; base < n; base += 64) {
    int i = base + lane;
    int v0 = (i < n) ? bcount[i] : 0;
    int v = v0;
    #pragma unroll
    for (int off = 1; off < 64; off <<= 1) {
      int t = __shfl_up(v, off, 64);
      if (lane >= off) v += t;
    }
    int incl = v + carry;
    if (i < n) {
      boffs[i + 1] = incl;
      gcursor[i] = incl - v0;   // exclusive = bucket base
    }
    carry = __shfl(incl, 63, 64);
  }
}

// per-block LDS histogram + 1 returning atomic per (block,bucket) + rank scatter
__global__ __launch_bounds__(256) void bwrite_kernel(const int* __restrict__ ei,
    int* __restrict__ gcursor, unsigned* __restrict__ bdata, int E, int NB) {
  __shared__ int hist[512];
  __shared__ int gbase[512];
  const int tid = threadIdx.x;
  const int total = 2 * E;
  const int base0 = blockIdx.x * WCHUNK;
  if (base0 >= total) return;
  const int cnt = min(WCHUNK, total - base0);
  for (int i = tid; i < 512; i += 256) hist[i] = 0;
  __syncthreads();
  for (int k = tid; k < cnt; k += 256)
    atomicAdd(&hist[((unsigned)ei[base0 + k]) >> 7], 1);
  __syncthreads();
  for (int b = tid; b < NB; b += 256) {
    int h = hist[b];
    gbase[b] = h ? atomicAdd(&gcursor[b], h) : 0;
  }
  __syncthreads();
  for (int i = tid; i < 512; i += 256) hist[i] = 0;
  __syncthreads();
  for (int k = tid; k < cnt; k += 256) {
    int i = base0 + k;
    int v = ei[i];
    int other = (i < E) ? ei[i + E] : ei[i - E];
    int b = ((unsigned)v) >> 7;
    int r = atomicAdd(&hist[b], 1);
    bdata[gbase[b] + r] = (((unsigned)(v & 127)) << 16) | (unsigned)other;
  }
}

// one block per bucket: LDS fp32 accumulator, wave-per-entry gather + ds_add
__global__ __launch_bounds__(512) void bagg_kernel(const unsigned short* __restrict__ xb,
    const float* __restrict__ eps, const int* __restrict__ boffs,
    const unsigned* __restrict__ bdata, unsigned short* __restrict__ aggb, int N) {
  __shared__ float acc[128 * 128];   // 64 KB
  const int tid = threadIdx.x;
  for (int i = tid; i < 16384; i += 512) acc[i] = 0.f;
  __syncthreads();
  const int b = blockIdx.x;
  const int beg = boffs[b], end = boffs[b + 1];
  const int wid = tid >> 6, lane = tid & 63;
  for (int p = beg + wid; p < end; p += 8) {
    unsigned e = bdata[p];
    int vloc = (int)(e >> 16);
    int other = (int)(e & 0xFFFFu);
    const unsigned short* row = xb + ((size_t)other << 7);
    float f0 = bf2f(row[lane]);
    float f1 = bf2f(row[lane + 64]);
    atomicAdd(&acc[(vloc << 7) + lane], f0);        // bank = lane%32: conflict-free
    atomicAdd(&acc[(vloc << 7) + 64 + lane], f1);
  }
  __syncthreads();
  float s = 1.0f + eps[0];
  int r = tid >> 2, c0 = (tid & 3) << 5;
  int n = (b << 7) + r;
  if (n < N) {
    #pragma unroll
    for (int j = 0; j < 4; ++j) {
      short8v o;
      #pragma unroll
      for (int m = 0; m < 8; ++m) {
        int c = c0 + j * 8 + m;
        o[m] = (short)f2bf(acc[(r << 7) + c] + s * bf2f(xb[((size_t)n << 7) + c]));
      }
      *(short8v*)(aggb + ((size_t)n << 7) + c0 + j * 8) = o;
    }
  }
}

// ================= legacy CSR kernels (fallback tiers) =================

__global__ __launch_bounds__(256) void zero_kernel(int* __restrict__ p, int n) {
  int i = blockIdx.x * blockDim.x + threadIdx.x;
  int stride = gridDim.x * blockDim.x;
  for (; i < n; i += stride) p[i] = 0;
}

__global__ __launch_bounds__(256) void count_kernel(const int* __restrict__ ei,
                                                    int* __restrict__ deg, int total) {
  int i = blockIdx.x * blockDim.x + threadIdx.x;
  int stride = gridDim.x * blockDim.x;
  for (; i < total; i += stride) atomicAdd(&deg[ei[i]], 1);
}

__global__ __launch_bounds__(64) void scan_kernel(const int* __restrict__ deg,
                                                  int* __restrict__ rowptr, int n) {
  int lane = threadIdx.x;
  int carry = 0;
  if (lane == 0) rowptr[0] = 0;
  for (int base = 0; base < n; base += 64) {
    int i = base + lane;
    int v = (i < n) ? deg[i] : 0;
    #pragma unroll
    for (int off = 1; off < 64; off <<= 1) {
      int t = __shfl_up(v, off, 64);
      if (lane >= off) v += t;
    }
    int incl = v + carry;
    if (i < n) rowptr[i + 1] = incl;
    carry = __shfl(incl, 63, 64);
  }
}

__global__ __launch_bounds__(256) void chunk_reduce_kernel(const int* __restrict__ deg,
                                                           int* __restrict__ csum, int n) {
  __shared__ int wsum[4];
  int base = blockIdx.x * 1024;
  int tid = threadIdx.x;
  int s = 0;
  #pragma unroll
  for (int j = 0; j < 4; ++j) {
    int i = base + tid * 4 + j;
    if (i < n) s += deg[i];
  }
  #pragma unroll
  for (int off = 1; off < 64; off <<= 1) s += __shfl_xor(s, off, 64);
  if ((tid & 63) == 0) wsum[tid >> 6] = s;
  __syncthreads();
  if (tid == 0) csum[blockIdx.x] = wsum[0] + wsum[1] + wsum[2] + wsum[3];
}

__global__ __launch_bounds__(256) void chunk_scan_c_kernel(const int* __restrict__ deg,
    const int* __restrict__ coffs, int* __restrict__ rowptr,
    int* __restrict__ cursor, int n) {
  __shared__ int wpart[4];
  int b = blockIdx.x;
  int base = b * 1024;
  int tid = threadIdx.x;
  int lane = tid & 63, wv = tid >> 6;
  int v[4], s = 0;
  #pragma unroll
  for (int j = 0; j < 4; ++j) {
    int i = base + tid * 4 + j;
    v[j] = (i < n) ? deg[i] : 0;
    s += v[j];
  }
  int incl = s;
  #pragma unroll
  for (int off = 1; off < 64; off <<= 1) {
    int t = __shfl_up(incl, off, 64);
    if (lane >= off) incl += t;
  }
  if (lane == 63) wpart[wv] = incl;
  __syncthreads();
  int woff = 0;
  for (int k = 0; k < wv; ++k) woff += wpart[k];
  int run = incl - s + woff + coffs[b];
  #pragma unroll
  for (int j = 0; j < 4; ++j) {
    int i = base + tid * 4 + j;
    if (i < n) {
      cursor[i] = run;
      run += v[j];
      rowptr[i + 1] = run;
    }
  }
  if (b == 0 && tid == 0) rowptr[0] = 0;
}

__global__ __launch_bounds__(256) void fill_batch_kernel(const int* __restrict__ ei,
    int* __restrict__ cursor, int* __restrict__ adj, int E) {
  int total = 2 * E;
  int T = gridDim.x * blockDim.x;
  int t = blockIdx.x * blockDim.x + threadIdx.x;
  int vv[FILLK], oo[FILLK], pp[FILLK];
  for (long long base = 0; base < total; base += (long long)T * FILLK) {
    #pragma unroll
    for (int k = 0; k < FILLK; ++k) {
      long long i = base + (long long)k * T + t;
      if (i < total) {
        int ii = (int)i;
        vv[k] = ei[ii];
        oo[k] = (ii < E) ? ei[ii + E] : ei[ii - E];
      } else {
        vv[k] = -1; oo[k] = 0;
      }
    }
    #pragma unroll
    for (int k = 0; k < FILLK; ++k)
      pp[k] = (vv[k] >= 0) ? atomicAdd(&cursor[vv[k]], 1) : 0;
    #pragma unroll
    for (int k = 0; k < FILLK; ++k)
      if (vv[k] >= 0) adj[pp[k]] = oo[k];
  }
}

__global__ __launch_bounds__(256) void aggb_kernel(const unsigned short* __restrict__ xb,
    const float* __restrict__ eps, const int* __restrict__ rowptr,
    const int* __restrict__ adj, unsigned short* __restrict__ aggb, int N) {
  int n = blockIdx.x * 16 + (threadIdx.x >> 4);
  if (n >= N) return;
  int lane = threadIdx.x & 15;
  float s = 1.0f + eps[0];
  const unsigned short* base = xb + (size_t)n * 128 + lane * 8;
  short8v own = *(const short8v*)base;
  float acc[8];
  #pragma unroll
  for (int j = 0; j < 8; ++j) acc[j] = bf2f((unsigned short)own[j]) * s;
  int beg = rowptr[n], end = rowptr[n + 1];
  for (int p = beg; p < end; ++p) {
    int nb = adj[p];
    short8v v = *(const short8v*)(xb + (size_t)nb * 128 + lane * 8);
    #pragma unroll
    for (int j = 0; j < 8; ++j) acc[j] += bf2f((unsigned short)v[j]);
  }
  short8v o;
  #pragma unroll
  for (int j = 0; j < 8; ++j) o[j] = (short)f2bf(acc[j]);
  *(short8v*)(aggb + (size_t)n * 128 + lane * 8) = o;
}

__global__ __launch_bounds__(256) void init_kernel(const float* __restrict__ x,
                                                   const float* __restrict__ eps,
                                                   float* __restrict__ agg, int total4) {
  float scale = 1.0f + eps[0];
  int idx = blockIdx.x * blockDim.x + threadIdx.x;
  int stride = gridDim.x * blockDim.x;
  const float4* x4 = (const float4*)x;
  float4* a4 = (float4*)agg;
  for (int i = idx; i < total4; i += stride) {
    float4 v = x4[i];
    v.x *= scale; v.y *= scale; v.z *= scale; v.w *= scale;
    a4[i] = v;
  }
}

__global__ __launch_bounds__(256) void scatter_kernel(const float* __restrict__ x,
    const int* __restrict__ src, const int* __restrict__ dst,
    float* __restrict__ agg, int E) {
  long long total = (long long)E * 32;
  long long idx = (long long)blockIdx.x * blockDim.x + threadIdx.x;
  long long stride = (long long)gridDim.x * blockDim.x;
  for (; idx < total; idx += stride) {
    int e = (int)(idx >> 5);
    int f4 = (int)(idx & 31);
    int s = src[e], d = dst[e];
    float4 xs = ((const float4*)x)[(size_t)s * 32 + f4];
    float4 xd = ((const float4*)x)[(size_t)d * 32 + f4];
    float* as = agg + (size_t)s * 128 + f4 * 4;
    float* ad = agg + (size_t)d * 128 + f4 * 4;
    atomicAdd(as + 0, xd.x); atomicAdd(as + 1, xd.y);
    atomicAdd(as + 2, xd.z); atomicAdd(as + 3, xd.w);
    atomicAdd(ad + 0, xs.x); atomicAdd(ad + 1, xs.y);
    atomicAdd(ad + 2, xs.z); atomicAdd(ad + 3, xs.w);
  }
}

// ---------------- MFMA MLP, bf16-agg input ----------------

__global__ __launch_bounds__(256) void mlp_mfma_b_kernel(
    const unsigned short* __restrict__ aggb, const short* __restrict__ w1p,
    const short* __restrict__ w2p, const float* __restrict__ b1,
    const float* __restrict__ b2, float* __restrict__ out, int N) {
  __shared__ short s_h[32 * 512];   // hmid bf16, XOR-swizzled, 32 KB
  const int tid = threadIdx.x;
  const int w = tid >> 6, l = tid & 63;
  const int l15 = l & 15, lg = l >> 4;
  const int brow = blockIdx.x * 32;

  short8v af[2][4];
  #pragma unroll
  for (int mt = 0; mt < 2; ++mt) {
    int row = brow + mt * 16 + l15;
    #pragma unroll
    for (int ks = 0; ks < 4; ++ks) {
      short8v s = (short8v)(short)0;
      if (row < N)
        s = *(const short8v*)(aggb + (size_t)row * 128 + ks * 32 + lg * 8);
      af[mt][ks] = s;
    }
  }

  f32x4 acc1[2][8];
  #pragma unroll
  for (int nt = 0; nt < 8; ++nt) {
    float bv = b1[(w * 8 + nt) * 16 + l15];
    acc1[0][nt] = (f32x4){bv, bv, bv, bv};
    acc1[1][nt] = (f32x4){bv, bv, bv, bv};
  }
  #pragma unroll
  for (int nt = 0; nt < 8; ++nt) {
    int ntg = w * 8 + nt;
    #pragma unroll
    for (int ks = 0; ks < 4; ++ks) {
      short8v bf = *(const short8v*)(w1p + ((ntg * 4 + ks) << 9) + l * 8);
      acc1[0][nt] = __builtin_amdgcn_mfma_f32_16x16x32_bf16(af[0][ks], bf, acc1[0][nt], 0, 0, 0);
      acc1[1][nt] = __builtin_amdgcn_mfma_f32_16x16x32_bf16(af[1][ks], bf, acc1[1][nt], 0, 0, 0);
    }
  }

  #pragma unroll
  for (int mt = 0; mt < 2; ++mt)
    #pragma unroll
    for (int nt = 0; nt < 8; ++nt) {
      int col = (w * 8 + nt) * 16 + l15;
      #pragma unroll
      for (int reg = 0; reg < 4; ++reg) {
        int row = mt * 16 + lg * 4 + reg;
        float v = fmaxf(acc1[mt][nt][reg], 0.f);
        int byte = (row << 10) + (col << 1);
        byte ^= (row & 7) << 4;
        *(short*)((char*)s_h + byte) = (short)f2bf(v);
      }
    }
  __syncthreads();

  f32x4 acc2[2][2];
  #pragma unroll
  for (int ntl = 0; ntl < 2; ++ntl) {
    float bv = b2[(w * 2 + ntl) * 16 + l15];
    acc2[0][ntl] = (f32x4){bv, bv, bv, bv};
    acc2[1][ntl] = (f32x4){bv, bv, bv, bv};
  }
  #pragma unroll
  for (int ks = 0; ks < 16; ++ks) {
    short8v a2[2];
    #pragma unroll
    for (int mt = 0; mt < 2; ++mt) {
      int row = mt * 16 + l15;
      int byte = (row << 10) + ((ks * 32 + lg * 8) << 1);
      byte ^= (row & 7) << 4;
      a2[mt] = *(short8v*)((char*)s_h + byte);
    }
    #pragma unroll
    for (int ntl = 0; ntl < 2; ++ntl) {
      int ntg = w * 2 + ntl;
      short8v bf = *(const short8v*)(w2p + ((ntg * 16 + ks) << 9) + l * 8);
      acc2[0][ntl] = __builtin_amdgcn_mfma_f32_16x16x32_bf16(a2[0], bf, acc2[0][ntl], 0, 0, 0);
      acc2[1][ntl] = __builtin_amdgcn_mfma_f32_16x16x32_bf16(a2[1], bf, acc2[1][ntl], 0, 0, 0);
    }
  }

  #pragma unroll
  for (int mt = 0; mt < 2; ++mt)
    #pragma unroll
    for (int ntl = 0; ntl < 2; ++ntl)
      #pragma unroll
      for (int reg = 0; reg < 4; ++reg) {
        int row = brow + mt * 16 + lg * 4 + reg;
        if (row < N)
          out[(size_t)row * 128 + (w * 2 + ntl) * 16 + l15] = acc2[mt][ntl][reg];
      }
}

// ---------------- fallback SIMT MLP (tier0) ----------------

__global__ __launch_bounds__(256) void mlp_kernel(
    const float* agg, const float* __restrict__ W1,
    const float* __restrict__ b1, const float* __restrict__ W2,
    const float* __restrict__ b2, float* out, int N) {
  __shared__ float s_agg[MROWS][128];
  __shared__ float s_h[MROWS][65];
  const int tid = threadIdx.x;
  const int block_row = blockIdx.x * MROWS;

  for (int i = tid; i < MROWS * 32; i += 256) {
    int r = i >> 5, c4 = i & 31;
    if (block_row + r < N)
      ((float4*)&s_agg[r][0])[c4] = ((const float4*)agg)[(size_t)(block_row + r) * 32 + c4];
    else
      ((float4*)&s_agg[r][0])[c4] = make_float4(0.f, 0.f, 0.f, 0.f);
  }
  __syncthreads();

  const int r = tid >> 3;
  const int f0 = (tid & 7) << 4;
  float acc[16];
  #pragma unroll
  for (int j = 0; j < 16; ++j) acc[j] = b2[f0 + j];

  const int hc = tid & 63;
  const int hr0 = tid >> 6;

  for (int h0 = 0; h0 < 512; h0 += 64) {
    float sum[8];
    float bv = b1[h0 + hc];
    #pragma unroll
    for (int j = 0; j < 8; ++j) sum[j] = bv;
    const float* w1col = W1 + h0 + hc;
    #pragma unroll 4
    for (int k = 0; k < 128; ++k) {
      float wv = w1col[(size_t)k * 512];
      #pragma unroll
      for (int j = 0; j < 8; ++j) sum[j] += s_agg[hr0 + (j << 2)][k] * wv;
    }
    __syncthreads();
    #pragma unroll
    for (int j = 0; j < 8; ++j) s_h[hr0 + (j << 2)][hc] = fmaxf(sum[j], 0.f);
    __syncthreads();

    for (int hcc = 0; hcc < 64; ++hcc) {
      float hv = s_h[r][hcc];
      const float4* w2p = (const float4*)(W2 + (size_t)(h0 + hcc) * 128 + f0);
      float4 w0 = w2p[0], w1v = w2p[1], w2v = w2p[2], w3v = w2p[3];
      acc[0]  += hv * w0.x;  acc[1]  += hv * w0.y;  acc[2]  += hv * w0.z;  acc[3]  += hv * w0.w;
      acc[4]  += hv * w1v.x; acc[5]  += hv * w1v.y; acc[6]  += hv * w1v.z; acc[7]  += hv * w1v.w;
      acc[8]  += hv * w2v.x; acc[9]  += hv * w2v.y; acc[10] += hv * w2v.z; acc[11] += hv * w2v.w;
      acc[12] += hv * w3v.x; acc[13] += hv * w3v.y; acc[14] += hv * w3v.z; acc[15] += hv * w3v.w;
    }
  }

  if (block_row + r < N) {
    float4* op = (float4*)(out + (size_t)(block_row + r) * 128 + f0);
    op[0] = make_float4(acc[0],  acc[1],  acc[2],  acc[3]);
    op[1] = make_float4(acc[4],  acc[5],  acc[6],  acc[7]);
    op[2] = make_float4(acc[8],  acc[9],  acc[10], acc[11]);
    op[3] = make_float4(acc[12], acc[13], acc[14], acc[15]);
  }
}

extern "C" void kernel_launch(void* const* d_in, const int* in_sizes, int n_in,
                              void* d_out, int out_size, void* d_ws, size_t ws_size,
                              hipStream_t stream) {
  const float* x   = (const float*)d_in[0];
  const int*   ei  = (const int*)d_in[1];
  const float* eps = (const float*)d_in[2];
  const float* W1  = (const float*)d_in[3];
  const float* b1  = (const float*)d_in[4];
  const float* W2  = (const float*)d_in[5];
  const float* b2  = (const float*)d_in[6];
  float* out = (float*)d_out;

  const int N = in_sizes[0] / 128;
  const int E = in_sizes[1] / 2;
  const int nChunks = (N + 1023) / 1024;
  const int NB = (N + 127) >> 7;
  int mblocks = (N + MROWS - 1) / MROWS;

  size_t wp_bytes = 2u * 65536u * sizeof(short);
  size_t xb_bytes = ((size_t)N * 128 * sizeof(short) + 15) & ~(size_t)15;

  // bucket-tier layout: bcount(NB) | gcursor(NB) | boffs(NB+1) | bdata(2E u32) | w | xb | aggb
  size_t bt_ints = (size_t)3 * NB + 1 + (size_t)2 * E;
  size_t bt_al = ((bt_ints * sizeof(int)) + 15) & ~(size_t)15;
  size_t need_bt = bt_al + wp_bytes + 2 * xb_bytes;

  // legacy layout: deg(N) | cursor(N) | rowptr(N+1) | adj(2E) | csum | coffs | w | xb | aggb
  size_t csr_ints = (size_t)(3 * N + 1 + 2 * E) + (size_t)(2 * nChunks + 1);
  size_t csr_al = ((csr_ints * sizeof(int)) + 15) & ~(size_t)15;
  size_t need_t1 = csr_al + wp_bytes;
  size_t need_t2 = need_t1 + 2 * xb_bytes;

  if (N <= 65536 && ws_size >= need_bt) {
    // ---- bucket tier: no CSR, LDS-accumulated bucket aggregation ----
    int* bcount  = (int*)d_ws;
    int* gcursor = bcount + NB;
    int* boffs   = gcursor + NB;           // NB+1
    unsigned* bdata = (unsigned*)(boffs + NB + 1);   // 2E
    short* w1p  = (short*)((char*)d_ws + bt_al);
    short* w2p  = w1p + 65536;
    unsigned short* xb   = (unsigned short*)((char*)d_ws + bt_al + wp_bytes);
    unsigned short* aggb = (unsigned short*)((char*)d_ws + bt_al + wp_bytes + xb_bytes);

    prep_kernel<<<2048, 256, 0, stream>>>(x, W1, W2, bcount, xb, w1p, w2p, N, 3 * NB + 1);
    bcount_kernel<<<256, 256, 0, stream>>>(ei, bcount, 2 * E, NB);
    scan_cur_kernel<<<1, 64, 0, stream>>>(bcount, boffs, gcursor, NB);
    int wblocks = (2 * E + WCHUNK - 1) / WCHUNK;
    bwrite_kernel<<<wblocks, 256, 0, stream>>>(ei, gcursor, bdata, E, NB);
    bagg_kernel<<<NB, 512, 0, stream>>>(xb, eps, boffs, bdata, aggb, N);
    mlp_mfma_b_kernel<<<mblocks, 256, 0, stream>>>(aggb, w1p, w2p, b1, b2, out, N);
  } else if (ws_size >= need_t2) {
    // ---- tier2 (R8): batched atomic fill + bf16 gather + MFMA MLP ----
    int* deg    = (int*)d_ws;
    int* cursor = deg + N;
    int* rowptr = cursor + N;
    int* adj    = rowptr + (N + 1);
    int* csum   = adj + 2 * E;
    int* coffs  = csum + nChunks;
    short* w1p  = (short*)((char*)d_ws + csr_al);
    short* w2p  = w1p + 65536;
    unsigned short* xb   = (unsigned short*)((char*)d_ws + need_t1);
    unsigned short* aggb = (unsigned short*)((char*)d_ws + need_t1 + xb_bytes);

    prep_kernel<<<2048, 256, 0, stream>>>(x, W1, W2, deg, xb, w1p, w2p, N, 2 * N);
    count_kernel<<<4096, 256, 0, stream>>>(ei, deg, 2 * E);
    chunk_reduce_kernel<<<nChunks, 256, 0, stream>>>(deg, csum, N);
    scan_kernel<<<1, 64, 0, stream>>>(csum, coffs, nChunks);
    chunk_scan_c_kernel<<<nChunks, 256, 0, stream>>>(deg, coffs, rowptr, cursor, N);
    int fblocks = (2 * E + 256 * FILLK - 1) / (256 * FILLK);
    fill_batch_kernel<<<fblocks, 256, 0, stream>>>(ei, cursor, adj, E);
    aggb_kernel<<<(N + 15) / 16, 256, 0, stream>>>(xb, eps, rowptr, adj, aggb, N);
    mlp_mfma_b_kernel<<<mblocks, 256, 0, stream>>>(aggb, w1p, w2p, b1, b2, out, N);
  } else {
    // ---- tier0: atomic scatter + SIMT MLP ----
    init_kernel<<<2048, 256, 0, stream>>>(x, eps, out, N * 32);
    scatter_kernel<<<4096, 256, 0, stream>>>(x, ei, ei + E, out, E);
    mlp_kernel<<<mblocks, 256, 0, stream>>>(out, W1, b1, W2, b2, out, N);
  }
}

// Round 11
// 171.255 us; speedup vs baseline: 8.4494x; 8.4494x over previous
//
#include <hip/hip_runtime.h>

#define MROWS 32
#define FILLK 8
#define WCHUNK 4096

typedef __attribute__((ext_vector_type(8))) short short8v;   // 8 bf16 = 4 VGPR
typedef __attribute__((ext_vector_type(4))) float f32x4;

__device__ __forceinline__ unsigned short f2bf(float f) {
  unsigned u = __builtin_bit_cast(unsigned, f);
  unsigned r = (u + 0x7fffu + ((u >> 16) & 1u)) >> 16;   // RNE
  return (unsigned short)r;
}
__device__ __forceinline__ float bf2f(unsigned short s) {
  return __builtin_bit_cast(float, (unsigned)s << 16);
}

// ---------------- prep: zero zn ints + x->bf16 + weight repack ----------------
__global__ __launch_bounds__(256) void prep_kernel(
    const float* __restrict__ x, const float* __restrict__ W1,
    const float* __restrict__ W2, int* __restrict__ zp,
    unsigned short* __restrict__ xb, short* __restrict__ w1p,
    short* __restrict__ w2p, int N, int zn) {
  const int Z = zn;
  const int X = 16 * N;
  const int grand = Z + X + 131072;
  int i = blockIdx.x * blockDim.x + threadIdx.x;
  int stride = gridDim.x * blockDim.x;
  for (; i < grand; i += stride) {
    if (i < Z) {
      zp[i] = 0;
    } else if (i < Z + X) {
      int t = i - Z;
      const float4* p = (const float4*)(x + (size_t)t * 8);
      float4 q0 = p[0], q1 = p[1];
      short8v s;
      s[0] = (short)f2bf(q0.x); s[1] = (short)f2bf(q0.y);
      s[2] = (short)f2bf(q0.z); s[3] = (short)f2bf(q0.w);
      s[4] = (short)f2bf(q1.x); s[5] = (short)f2bf(q1.y);
      s[6] = (short)f2bf(q1.z); s[7] = (short)f2bf(q1.w);
      *(short8v*)(xb + (size_t)t * 8) = s;
    } else {
      int t = i - Z - X;          // 0..131071
      int idx = t & 65535;
      int frag = idx >> 9, rem = idx & 511;
      int lane = rem >> 3, j = rem & 7;
      if (t < 65536) {
        int nt = frag >> 2, ks = frag & 3;
        int k = ks * 32 + (lane >> 4) * 8 + j;
        int c = nt * 16 + (lane & 15);
        w1p[idx] = (short)f2bf(W1[k * 512 + c]);
      } else {
        int nt = frag >> 4, ks = frag & 15;
        int k = ks * 32 + (lane >> 4) * 8 + j;
        int c = nt * 16 + (lane & 15);
        w2p[idx] = (short)f2bf(W2[k * 128 + c]);
      }
    }
  }
}

// ================= bucket path (N <= 65536); bucket = node>>7 =================

__global__ __launch_bounds__(256) void bcount_kernel(const int* __restrict__ ei,
    int* __restrict__ bcount, int total, int NB) {
  __shared__ int hist[512];
  for (int i = threadIdx.x; i < 512; i += 256) hist[i] = 0;
  __syncthreads();
  int i = blockIdx.x * blockDim.x + threadIdx.x;
  int stride = gridDim.x * blockDim.x;
  for (; i < total; i += stride) atomicAdd(&hist[((unsigned)ei[i]) >> 7], 1);
  __syncthreads();
  for (int b = threadIdx.x; b < NB; b += 256)
    if (hist[b]) atomicAdd(&bcount[b], hist[b]);   // non-returning: fast
}

// single-wave exclusive scan over NB buckets -> boffs[0..NB], gcursor[b]=boffs[b]
__global__ __launch_bounds__(64) void scan_cur_kernel(const int* __restrict__ bcount,
    int* __restrict__ boffs, int* __restrict__ gcursor, int n) {
  int lane = threadIdx.x;
  int carry = 0;
  if (lane == 0) boffs[0] = 0;
  for (int base = 0; base < n; base += 64) {
    int i = base + lane;
    int v0 = (i < n) ? bcount[i] : 0;
    int v = v0;
    #pragma unroll
    for (int off = 1; off < 64; off <<= 1) {
      int t = __shfl_up(v, off, 64);
      if (lane >= off) v += t;
    }
    int incl = v + carry;
    if (i < n) {
      boffs[i + 1] = incl;
      gcursor[i] = incl - v0;   // exclusive = bucket base
    }
    carry = __shfl(incl, 63, 64);
  }
}

// per-block LDS histogram + 1 returning atomic per (block,bucket) + rank scatter
__global__ __launch_bounds__(256) void bwrite_kernel(const int* __restrict__ ei,
    int* __restrict__ gcursor, unsigned* __restrict__ bdata, int E, int NB) {
  __shared__ int hist[512];
  __shared__ int gbase[512];
  const int tid = threadIdx.x;
  const int total = 2 * E;
  const int base0 = blockIdx.x * WCHUNK;
  if (base0 >= total) return;
  const int cnt = min(WCHUNK, total - base0);
  for (int i = tid; i < 512; i += 256) hist[i] = 0;
  __syncthreads();
  for (int k = tid; k < cnt; k += 256)
    atomicAdd(&hist[((unsigned)ei[base0 + k]) >> 7], 1);
  __syncthreads();
  for (int b = tid; b < NB; b += 256) {
    int h = hist[b];
    gbase[b] = h ? atomicAdd(&gcursor[b], h) : 0;
  }
  __syncthreads();
  for (int i = tid; i < 512; i += 256) hist[i] = 0;
  __syncthreads();
  for (int k = tid; k < cnt; k += 256) {
    int i = base0 + k;
    int v = ei[i];
    int other = (i < E) ? ei[i + E] : ei[i - E];
    int b = ((unsigned)v) >> 7;
    int r = atomicAdd(&hist[b], 1);
    bdata[gbase[b] + r] = (((unsigned)(v & 127)) << 16) | (unsigned)other;
  }
}

// per-bucket counting sort: bdata segment -> node-sorted u16 'other' + rowptr
__global__ __launch_bounds__(256) void bsort_kernel(const unsigned* __restrict__ bdata,
    const int* __restrict__ boffs, unsigned short* __restrict__ adj2,
    int* __restrict__ rowptr, int N, int E2) {
  __shared__ int hist[128];
  __shared__ int loff[129];
  __shared__ int cur[128];
  const int b = blockIdx.x;
  const int beg = boffs[b], end = boffs[b + 1];
  const int tid = threadIdx.x;
  if (tid < 128) hist[tid] = 0;
  __syncthreads();
  for (int p = beg + tid; p < end; p += 256)
    atomicAdd(&hist[bdata[p] >> 16], 1);
  __syncthreads();
  if (tid < 64) {
    int a0 = hist[tid], a1 = hist[tid + 64];
    int v0 = a0;
    #pragma unroll
    for (int off = 1; off < 64; off <<= 1) {
      int t = __shfl_up(v0, off, 64);
      if (tid >= off) v0 += t;
    }
    int tot0 = __shfl(v0, 63, 64);
    int v1 = a1;
    #pragma unroll
    for (int off = 1; off < 64; off <<= 1) {
      int t = __shfl_up(v1, off, 64);
      if (tid >= off) v1 += t;
    }
    loff[tid] = v0 - a0;
    loff[tid + 64] = tot0 + v1 - a1;
    cur[tid] = v0 - a0;
    cur[tid + 64] = tot0 + v1 - a1;
    // rowptr = bucket base + local exclusive offset
    int n0 = (b << 7) + tid;
    int n1 = n0 + 64;
    if (n0 < N) rowptr[n0] = beg + loff[tid];
    if (n1 < N) rowptr[n1] = beg + loff[tid + 64];
  }
  if (b == 0 && tid == 0) rowptr[N] = E2;
  __syncthreads();
  for (int p = beg + tid; p < end; p += 256) {
    unsigned e = bdata[p];
    int r = atomicAdd(&cur[e >> 16], 1);
    adj2[beg + r] = (unsigned short)(e & 0xFFFFu);
  }
}

// bf16 gather-aggregate over sorted u16 adjacency: 16 lanes/node, fp32 accum
__global__ __launch_bounds__(256) void aggb_s_kernel(const unsigned short* __restrict__ xb,
    const float* __restrict__ eps, const int* __restrict__ rowptr,
    const unsigned short* __restrict__ adj2, unsigned short* __restrict__ aggb, int N) {
  int n = blockIdx.x * 16 + (threadIdx.x >> 4);
  if (n >= N) return;
  int lane = threadIdx.x & 15;
  float s = 1.0f + eps[0];
  const unsigned short* base = xb + (size_t)n * 128 + lane * 8;
  short8v own = *(const short8v*)base;
  float acc[8];
  #pragma unroll
  for (int j = 0; j < 8; ++j) acc[j] = bf2f((unsigned short)own[j]) * s;
  int beg = rowptr[n], end = rowptr[n + 1];
  for (int p = beg; p < end; ++p) {
    int nb = adj2[p];
    short8v v = *(const short8v*)(xb + (size_t)nb * 128 + lane * 8);
    #pragma unroll
    for (int j = 0; j < 8; ++j) acc[j] += bf2f((unsigned short)v[j]);
  }
  short8v o;
  #pragma unroll
  for (int j = 0; j < 8; ++j) o[j] = (short)f2bf(acc[j]);
  *(short8v*)(aggb + (size_t)n * 128 + lane * 8) = o;
}

// ================= legacy CSR kernels (tier2 fallback) =================

__global__ __launch_bounds__(256) void count_kernel(const int* __restrict__ ei,
                                                    int* __restrict__ deg, int total) {
  int i = blockIdx.x * blockDim.x + threadIdx.x;
  int stride = gridDim.x * blockDim.x;
  for (; i < total; i += stride) atomicAdd(&deg[ei[i]], 1);
}

__global__ __launch_bounds__(64) void scan_kernel(const int* __restrict__ deg,
                                                  int* __restrict__ rowptr, int n) {
  int lane = threadIdx.x;
  int carry = 0;
  if (lane == 0) rowptr[0] = 0;
  for (int base = 0; base < n; base += 64) {
    int i = base + lane;
    int v = (i < n) ? deg[i] : 0;
    #pragma unroll
    for (int off = 1; off < 64; off <<= 1) {
      int t = __shfl_up(v, off, 64);
      if (lane >= off) v += t;
    }
    int incl = v + carry;
    if (i < n) rowptr[i + 1] = incl;
    carry = __shfl(incl, 63, 64);
  }
}

__global__ __launch_bounds__(256) void chunk_reduce_kernel(const int* __restrict__ deg,
                                                           int* __restrict__ csum, int n) {
  __shared__ int wsum[4];
  int base = blockIdx.x * 1024;
  int tid = threadIdx.x;
  int s = 0;
  #pragma unroll
  for (int j = 0; j < 4; ++j) {
    int i = base + tid * 4 + j;
    if (i < n) s += deg[i];
  }
  #pragma unroll
  for (int off = 1; off < 64; off <<= 1) s += __shfl_xor(s, off, 64);
  if ((tid & 63) == 0) wsum[tid >> 6] = s;
  __syncthreads();
  if (tid == 0) csum[blockIdx.x] = wsum[0] + wsum[1] + wsum[2] + wsum[3];
}

__global__ __launch_bounds__(256) void chunk_scan_c_kernel(const int* __restrict__ deg,
    const int* __restrict__ coffs, int* __restrict__ rowptr,
    int* __restrict__ cursor, int n) {
  __shared__ int wpart[4];
  int b = blockIdx.x;
  int base = b * 1024;
  int tid = threadIdx.x;
  int lane = tid & 63, wv = tid >> 6;
  int v[4], s = 0;
  #pragma unroll
  for (int j = 0; j < 4; ++j) {
    int i = base + tid * 4 + j;
    v[j] = (i < n) ? deg[i] : 0;
    s += v[j];
  }
  int incl = s;
  #pragma unroll
  for (int off = 1; off < 64; off <<= 1) {
    int t = __shfl_up(incl, off, 64);
    if (lane >= off) incl += t;
  }
  if (lane == 63) wpart[wv] = incl;
  __syncthreads();
  int woff = 0;
  for (int k = 0; k < wv; ++k) woff += wpart[k];
  int run = incl - s + woff + coffs[b];
  #pragma unroll
  for (int j = 0; j < 4; ++j) {
    int i = base + tid * 4 + j;
    if (i < n) {
      cursor[i] = run;
      run += v[j];
      rowptr[i + 1] = run;
    }
  }
  if (b == 0 && tid == 0) rowptr[0] = 0;
}

__global__ __launch_bounds__(256) void fill_batch_kernel(const int* __restrict__ ei,
    int* __restrict__ cursor, int* __restrict__ adj, int E) {
  int total = 2 * E;
  int T = gridDim.x * blockDim.x;
  int t = blockIdx.x * blockDim.x + threadIdx.x;
  int vv[FILLK], oo[FILLK], pp[FILLK];
  for (long long base = 0; base < total; base += (long long)T * FILLK) {
    #pragma unroll
    for (int k = 0; k < FILLK; ++k) {
      long long i = base + (long long)k * T + t;
      if (i < total) {
        int ii = (int)i;
        vv[k] = ei[ii];
        oo[k] = (ii < E) ? ei[ii + E] : ei[ii - E];
      } else {
        vv[k] = -1; oo[k] = 0;
      }
    }
    #pragma unroll
    for (int k = 0; k < FILLK; ++k)
      pp[k] = (vv[k] >= 0) ? atomicAdd(&cursor[vv[k]], 1) : 0;
    #pragma unroll
    for (int k = 0; k < FILLK; ++k)
      if (vv[k] >= 0) adj[pp[k]] = oo[k];
  }
}

__global__ __launch_bounds__(256) void aggb_kernel(const unsigned short* __restrict__ xb,
    const float* __restrict__ eps, const int* __restrict__ rowptr,
    const int* __restrict__ adj, unsigned short* __restrict__ aggb, int N) {
  int n = blockIdx.x * 16 + (threadIdx.x >> 4);
  if (n >= N) return;
  int lane = threadIdx.x & 15;
  float s = 1.0f + eps[0];
  const unsigned short* base = xb + (size_t)n * 128 + lane * 8;
  short8v own = *(const short8v*)base;
  float acc[8];
  #pragma unroll
  for (int j = 0; j < 8; ++j) acc[j] = bf2f((unsigned short)own[j]) * s;
  int beg = rowptr[n], end = rowptr[n + 1];
  for (int p = beg; p < end; ++p) {
    int nb = adj[p];
    short8v v = *(const short8v*)(xb + (size_t)nb * 128 + lane * 8);
    #pragma unroll
    for (int j = 0; j < 8; ++j) acc[j] += bf2f((unsigned short)v[j]);
  }
  short8v o;
  #pragma unroll
  for (int j = 0; j < 8; ++j) o[j] = (short)f2bf(acc[j]);
  *(short8v*)(aggb + (size_t)n * 128 + lane * 8) = o;
}

// ---------------- tier0 ----------------

__global__ __launch_bounds__(256) void init_kernel(const float* __restrict__ x,
                                                   const float* __restrict__ eps,
                                                   float* __restrict__ agg, int total4) {
  float scale = 1.0f + eps[0];
  int idx = blockIdx.x * blockDim.x + threadIdx.x;
  int stride = gridDim.x * blockDim.x;
  const float4* x4 = (const float4*)x;
  float4* a4 = (float4*)agg;
  for (int i = idx; i < total4; i += stride) {
    float4 v = x4[i];
    v.x *= scale; v.y *= scale; v.z *= scale; v.w *= scale;
    a4[i] = v;
  }
}

__global__ __launch_bounds__(256) void scatter_kernel(const float* __restrict__ x,
    const int* __restrict__ src, const int* __restrict__ dst,
    float* __restrict__ agg, int E) {
  long long total = (long long)E * 32;
  long long idx = (long long)blockIdx.x * blockDim.x + threadIdx.x;
  long long stride = (long long)gridDim.x * blockDim.x;
  for (; idx < total; idx += stride) {
    int e = (int)(idx >> 5);
    int f4 = (int)(idx & 31);
    int s = src[e], d = dst[e];
    float4 xs = ((const float4*)x)[(size_t)s * 32 + f4];
    float4 xd = ((const float4*)x)[(size_t)d * 32 + f4];
    float* as = agg + (size_t)s * 128 + f4 * 4;
    float* ad = agg + (size_t)d * 128 + f4 * 4;
    atomicAdd(as + 0, xd.x); atomicAdd(as + 1, xd.y);
    atomicAdd(as + 2, xd.z); atomicAdd(as + 3, xd.w);
    atomicAdd(ad + 0, xs.x); atomicAdd(ad + 1, xs.y);
    atomicAdd(ad + 2, xs.z); atomicAdd(ad + 3, xs.w);
  }
}

// ---------------- MFMA MLP, bf16-agg input ----------------

__global__ __launch_bounds__(256) void mlp_mfma_b_kernel(
    const unsigned short* __restrict__ aggb, const short* __restrict__ w1p,
    const short* __restrict__ w2p, const float* __restrict__ b1,
    const float* __restrict__ b2, float* __restrict__ out, int N) {
  __shared__ short s_h[32 * 512];   // hmid bf16, XOR-swizzled, 32 KB
  const int tid = threadIdx.x;
  const int w = tid >> 6, l = tid & 63;
  const int l15 = l & 15, lg = l >> 4;
  const int brow = blockIdx.x * 32;

  short8v af[2][4];
  #pragma unroll
  for (int mt = 0; mt < 2; ++mt) {
    int row = brow + mt * 16 + l15;
    #pragma unroll
    for (int ks = 0; ks < 4; ++ks) {
      short8v s = (short8v)(short)0;
      if (row < N)
        s = *(const short8v*)(aggb + (size_t)row * 128 + ks * 32 + lg * 8);
      af[mt][ks] = s;
    }
  }

  f32x4 acc1[2][8];
  #pragma unroll
  for (int nt = 0; nt < 8; ++nt) {
    float bv = b1[(w * 8 + nt) * 16 + l15];
    acc1[0][nt] = (f32x4){bv, bv, bv, bv};
    acc1[1][nt] = (f32x4){bv, bv, bv, bv};
  }
  #pragma unroll
  for (int nt = 0; nt < 8; ++nt) {
    int ntg = w * 8 + nt;
    #pragma unroll
    for (int ks = 0; ks < 4; ++ks) {
      short8v bf = *(const short8v*)(w1p + ((ntg * 4 + ks) << 9) + l * 8);
      acc1[0][nt] = __builtin_amdgcn_mfma_f32_16x16x32_bf16(af[0][ks], bf, acc1[0][nt], 0, 0, 0);
      acc1[1][nt] = __builtin_amdgcn_mfma_f32_16x16x32_bf16(af[1][ks], bf, acc1[1][nt], 0, 0, 0);
    }
  }

  #pragma unroll
  for (int mt = 0; mt < 2; ++mt)
    #pragma unroll
    for (int nt = 0; nt < 8; ++nt) {
      int col = (w * 8 + nt) * 16 + l15;
      #pragma unroll
      for (int reg = 0; reg < 4; ++reg) {
        int row = mt * 16 + lg * 4 + reg;
        float v = fmaxf(acc1[mt][nt][reg], 0.f);
        int byte = (row << 10) + (col << 1);
        byte ^= (row & 7) << 4;
        *(short*)((char*)s_h + byte) = (short)f2bf(v);
      }
    }
  __syncthreads();

  f32x4 acc2[2][2];
  #pragma unroll
  for (int ntl = 0; ntl < 2; ++ntl) {
    float bv = b2[(w * 2 + ntl) * 16 + l15];
    acc2[0][ntl] = (f32x4){bv, bv, bv, bv};
    acc2[1][ntl] = (f32x4){bv, bv, bv, bv};
  }
  #pragma unroll
  for (int ks = 0; ks < 16; ++ks) {
    short8v a2[2];
    #pragma unroll
    for (int mt = 0; mt < 2; ++mt) {
      int row = mt * 16 + l15;
      int byte = (row << 10) + ((ks * 32 + lg * 8) << 1);
      byte ^= (row & 7) << 4;
      a2[mt] = *(short8v*)((char*)s_h + byte);
    }
    #pragma unroll
    for (int ntl = 0; ntl < 2; ++ntl) {
      int ntg = w * 2 + ntl;
      short8v bf = *(const short8v*)(w2p + ((ntg * 16 + ks) << 9) + l * 8);
      acc2[0][ntl] = __builtin_amdgcn_mfma_f32_16x16x32_bf16(a2[0], bf, acc2[0][ntl], 0, 0, 0);
      acc2[1][ntl] = __builtin_amdgcn_mfma_f32_16x16x32_bf16(a2[1], bf, acc2[1][ntl], 0, 0, 0);
    }
  }

  #pragma unroll
  for (int mt = 0; mt < 2; ++mt)
    #pragma unroll
    for (int ntl = 0; ntl < 2; ++ntl)
      #pragma unroll
      for (int reg = 0; reg < 4; ++reg) {
        int row = brow + mt * 16 + lg * 4 + reg;
        if (row < N)
          out[(size_t)row * 128 + (w * 2 + ntl) * 16 + l15] = acc2[mt][ntl][reg];
      }
}

// ---------------- fallback SIMT MLP (tier0) ----------------

__global__ __launch_bounds__(256) void mlp_kernel(
    const float* agg, const float* __restrict__ W1,
    const float* __restrict__ b1, const float* __restrict__ W2,
    const float* __restrict__ b2, float* out, int N) {
  __shared__ float s_agg[MROWS][128];
  __shared__ float s_h[MROWS][65];
  const int tid = threadIdx.x;
  const int block_row = blockIdx.x * MROWS;

  for (int i = tid; i < MROWS * 32; i += 256) {
    int r = i >> 5, c4 = i & 31;
    if (block_row + r < N)
      ((float4*)&s_agg[r][0])[c4] = ((const float4*)agg)[(size_t)(block_row + r) * 32 + c4];
    else
      ((float4*)&s_agg[r][0])[c4] = make_float4(0.f, 0.f, 0.f, 0.f);
  }
  __syncthreads();

  const int r = tid >> 3;
  const int f0 = (tid & 7) << 4;
  float acc[16];
  #pragma unroll
  for (int j = 0; j < 16; ++j) acc[j] = b2[f0 + j];

  const int hc = tid & 63;
  const int hr0 = tid >> 6;

  for (int h0 = 0; h0 < 512; h0 += 64) {
    float sum[8];
    float bv = b1[h0 + hc];
    #pragma unroll
    for (int j = 0; j < 8; ++j) sum[j] = bv;
    const float* w1col = W1 + h0 + hc;
    #pragma unroll 4
    for (int k = 0; k < 128; ++k) {
      float wv = w1col[(size_t)k * 512];
      #pragma unroll
      for (int j = 0; j < 8; ++j) sum[j] += s_agg[hr0 + (j << 2)][k] * wv;
    }
    __syncthreads();
    #pragma unroll
    for (int j = 0; j < 8; ++j) s_h[hr0 + (j << 2)][hc] = fmaxf(sum[j], 0.f);
    __syncthreads();

    for (int hcc = 0; hcc < 64; ++hcc) {
      float hv = s_h[r][hcc];
      const float4* w2p = (const float4*)(W2 + (size_t)(h0 + hcc) * 128 + f0);
      float4 w0 = w2p[0], w1v = w2p[1], w2v = w2p[2], w3v = w2p[3];
      acc[0]  += hv * w0.x;  acc[1]  += hv * w0.y;  acc[2]  += hv * w0.z;  acc[3]  += hv * w0.w;
      acc[4]  += hv * w1v.x; acc[5]  += hv * w1v.y; acc[6]  += hv * w1v.z; acc[7]  += hv * w1v.w;
      acc[8]  += hv * w2v.x; acc[9]  += hv * w2v.y; acc[10] += hv * w2v.z; acc[11] += hv * w2v.w;
      acc[12] += hv * w3v.x; acc[13] += hv * w3v.y; acc[14] += hv * w3v.z; acc[15] += hv * w3v.w;
    }
  }

  if (block_row + r < N) {
    float4* op = (float4*)(out + (size_t)(block_row + r) * 128 + f0);
    op[0] = make_float4(acc[0],  acc[1],  acc[2],  acc[3]);
    op[1] = make_float4(acc[4],  acc[5],  acc[6],  acc[7]);
    op[2] = make_float4(acc[8],  acc[9],  acc[10], acc[11]);
    op[3] = make_float4(acc[12], acc[13], acc[14], acc[15]);
  }
}

extern "C" void kernel_launch(void* const* d_in, const int* in_sizes, int n_in,
                              void* d_out, int out_size, void* d_ws, size_t ws_size,
                              hipStream_t stream) {
  const float* x   = (const float*)d_in[0];
  const int*   ei  = (const int*)d_in[1];
  const float* eps = (const float*)d_in[2];
  const float* W1  = (const float*)d_in[3];
  const float* b1  = (const float*)d_in[4];
  const float* W2  = (const float*)d_in[5];
  const float* b2  = (const float*)d_in[6];
  float* out = (float*)d_out;

  const int N = in_sizes[0] / 128;
  const int E = in_sizes[1] / 2;
  const int nChunks = (N + 1023) / 1024;
  const int NB = (N + 127) >> 7;
  int mblocks = (N + MROWS - 1) / MROWS;

  size_t wp_bytes = 2u * 65536u * sizeof(short);
  size_t xb_bytes = ((size_t)N * 128 * sizeof(short) + 15) & ~(size_t)15;

  // bucket+sort layout: bcount(NB) | gcursor(NB) | boffs(NB+1) | rowptr(N+1) |
  //                     bdata(2E u32) | adj2(2E u16 = E+1 ints) | w | xb | aggb
  size_t bt_ints = (size_t)2 * NB + (NB + 1) + (size_t)(N + 1) + (size_t)2 * E + (size_t)(E + 1);
  size_t bt_al = ((bt_ints * sizeof(int)) + 15) & ~(size_t)15;
  size_t need_bt = bt_al + wp_bytes + 2 * xb_bytes;

  // tier2 layout: deg(N) | cursor(N) | rowptr(N+1) | adj(2E) | csum | coffs | w | xb | aggb
  size_t csr_ints = (size_t)(3 * N + 1 + 2 * E) + (size_t)(2 * nChunks + 1);
  size_t csr_al = ((csr_ints * sizeof(int)) + 15) & ~(size_t)15;
  size_t need_t1 = csr_al + wp_bytes;
  size_t need_t2 = need_t1 + 2 * xb_bytes;

  if (N <= 65536 && ws_size >= need_bt) {
    // ---- bucket+sort tier ----
    int* bcount  = (int*)d_ws;
    int* gcursor = bcount + NB;
    int* boffs   = gcursor + NB;                     // NB+1
    int* rowptr  = boffs + NB + 1;                   // N+1
    unsigned* bdata = (unsigned*)(rowptr + N + 1);   // 2E
    unsigned short* adj2 = (unsigned short*)(bdata + 2 * E);  // 2E u16
    short* w1p  = (short*)((char*)d_ws + bt_al);
    short* w2p  = w1p + 65536;
    unsigned short* xb   = (unsigned short*)((char*)d_ws + bt_al + wp_bytes);
    unsigned short* aggb = (unsigned short*)((char*)d_ws + bt_al + wp_bytes + xb_bytes);

    prep_kernel<<<2048, 256, 0, stream>>>(x, W1, W2, bcount, xb, w1p, w2p, N, NB);
    bcount_kernel<<<256, 256, 0, stream>>>(ei, bcount, 2 * E, NB);
    scan_cur_kernel<<<1, 64, 0, stream>>>(bcount, boffs, gcursor, NB);
    int wblocks = (2 * E + WCHUNK - 1) / WCHUNK;
    bwrite_kernel<<<wblocks, 256, 0, stream>>>(ei, gcursor, bdata, E, NB);
    bsort_kernel<<<NB, 256, 0, stream>>>(bdata, boffs, adj2, rowptr, N, 2 * E);
    aggb_s_kernel<<<(N + 15) / 16, 256, 0, stream>>>(xb, eps, rowptr, adj2, aggb, N);
    mlp_mfma_b_kernel<<<mblocks, 256, 0, stream>>>(aggb, w1p, w2p, b1, b2, out, N);
  } else if (ws_size >= need_t2) {
    // ---- tier2 (R8): batched atomic fill + bf16 gather + MFMA MLP ----
    int* deg    = (int*)d_ws;
    int* cursor = deg + N;
    int* rowptr = cursor + N;
    int* adj    = rowptr + (N + 1);
    int* csum   = adj + 2 * E;
    int* coffs  = csum + nChunks;
    short* w1p  = (short*)((char*)d_ws + csr_al);
    short* w2p  = w1p + 65536;
    unsigned short* xb   = (unsigned short*)((char*)d_ws + need_t1);
    unsigned short* aggb = (unsigned short*)((char*)d_ws + need_t1 + xb_bytes);

    prep_kernel<<<2048, 256, 0, stream>>>(x, W1, W2, deg, xb, w1p, w2p, N, 2 * N);
    count_kernel<<<4096, 256, 0, stream>>>(ei, deg, 2 * E);
    chunk_reduce_kernel<<<nChunks, 256, 0, stream>>>(deg, csum, N);
    scan_kernel<<<1, 64, 0, stream>>>(csum, coffs, nChunks);
    chunk_scan_c_kernel<<<nChunks, 256, 0, stream>>>(deg, coffs, rowptr, cursor, N);
    int fblocks = (2 * E + 256 * FILLK - 1) / (256 * FILLK);
    fill_batch_kernel<<<fblocks, 256, 0, stream>>>(ei, cursor, adj, E);
    aggb_kernel<<<(N + 15) / 16, 256, 0, stream>>>(xb, eps, rowptr, adj, aggb, N);
    mlp_mfma_b_kernel<<<mblocks, 256, 0, stream>>>(aggb, w1p, w2p, b1, b2, out, N);
  } else {
    // ---- tier0 ----
    init_kernel<<<2048, 256, 0, stream>>>(x, eps, out, N * 32);
    scatter_kernel<<<4096, 256, 0, stream>>>(x, ei, ei + E, out, E);
    mlp_kernel<<<mblocks, 256, 0, stream>>>(out, W1, b1, W2, b2, out, N);
  }
}

// Round 13
// 162.800 us; speedup vs baseline: 8.8882x; 1.0519x over previous
//
#include <hip/hip_runtime.h>

#define MROWS 32
#define FILLK 8
#define WCHUNK 4096

typedef __attribute__((ext_vector_type(8))) short short8v;   // 8 bf16 = 4 VGPR
typedef __attribute__((ext_vector_type(4))) float f32x4;

__device__ __forceinline__ unsigned short f2bf(float f) {
  unsigned u = __builtin_bit_cast(unsigned, f);
  unsigned r = (u + 0x7fffu + ((u >> 16) & 1u)) >> 16;   // RNE
  return (unsigned short)r;
}
__device__ __forceinline__ float bf2f(unsigned short s) {
  return __builtin_bit_cast(float, (unsigned)s << 16);
}

// ---------------- prep: zero zn ints + x->bf16 + weight repack ----------------
__global__ __launch_bounds__(256) void prep_kernel(
    const float* __restrict__ x, const float* __restrict__ W1,
    const float* __restrict__ W2, int* __restrict__ zp,
    unsigned short* __restrict__ xb, short* __restrict__ w1p,
    short* __restrict__ w2p, int N, int zn) {
  const int Z = zn;
  const int X = 16 * N;
  const int grand = Z + X + 131072;
  int i = blockIdx.x * blockDim.x + threadIdx.x;
  int stride = gridDim.x * blockDim.x;
  for (; i < grand; i += stride) {
    if (i < Z) {
      zp[i] = 0;
    } else if (i < Z + X) {
      int t = i - Z;
      const float4* p = (const float4*)(x + (size_t)t * 8);
      float4 q0 = p[0], q1 = p[1];
      short8v s;
      s[0] = (short)f2bf(q0.x); s[1] = (short)f2bf(q0.y);
      s[2] = (short)f2bf(q0.z); s[3] = (short)f2bf(q0.w);
      s[4] = (short)f2bf(q1.x); s[5] = (short)f2bf(q1.y);
      s[6] = (short)f2bf(q1.z); s[7] = (short)f2bf(q1.w);
      *(short8v*)(xb + (size_t)t * 8) = s;
    } else {
      int t = i - Z - X;          // 0..131071
      int idx = t & 65535;
      int frag = idx >> 9, rem = idx & 511;
      int lane = rem >> 3, j = rem & 7;
      if (t < 65536) {
        int nt = frag >> 2, ks = frag & 3;
        int k = ks * 32 + (lane >> 4) * 8 + j;
        int c = nt * 16 + (lane & 15);
        w1p[idx] = (short)f2bf(W1[k * 512 + c]);
      } else {
        int nt = frag >> 4, ks = frag & 15;
        int k = ks * 32 + (lane >> 4) * 8 + j;
        int c = nt * 16 + (lane & 15);
        w2p[idx] = (short)f2bf(W2[k * 128 + c]);
      }
    }
  }
}

// ================= bucket path (N <= 65536); bucket = node>>7 =================

__global__ __launch_bounds__(256) void bcount_kernel(const int* __restrict__ ei,
    int* __restrict__ bcount, int total, int NB) {
  __shared__ int hist[512];
  for (int i = threadIdx.x; i < 512; i += 256) hist[i] = 0;
  __syncthreads();
  int i = blockIdx.x * blockDim.x + threadIdx.x;
  int stride = gridDim.x * blockDim.x;
  for (; i < total; i += stride) atomicAdd(&hist[((unsigned)ei[i]) >> 7], 1);
  __syncthreads();
  for (int b = threadIdx.x; b < NB; b += 256)
    if (hist[b]) atomicAdd(&bcount[b], hist[b]);   // non-returning: fast
}

// single-wave exclusive scan over NB buckets -> boffs[0..NB], gcursor[b]=boffs[b]
__global__ __launch_bounds__(64) void scan_cur_kernel(const int* __restrict__ bcount,
    int* __restrict__ boffs, int* __restrict__ gcursor, int n) {
  int lane = threadIdx.x;
  int carry = 0;
  if (lane == 0) boffs[0] = 0;
  for (int base = 0; base < n; base += 64) {
    int i = base + lane;
    int v0 = (i < n) ? bcount[i] : 0;
    int v = v0;
    #pragma unroll
    for (int off = 1; off < 64; off <<= 1) {
      int t = __shfl_up(v, off, 64);
      if (lane >= off) v += t;
    }
    int incl = v + carry;
    if (i < n) {
      boffs[i + 1] = incl;
      gcursor[i] = incl - v0;   // exclusive = bucket base
    }
    carry = __shfl(incl, 63, 64);
  }
}

// per-block LDS histogram + 1 returning atomic per (block,bucket) + rank scatter
__global__ __launch_bounds__(256) void bwrite_kernel(const int* __restrict__ ei,
    int* __restrict__ gcursor, unsigned* __restrict__ bdata, int E, int NB) {
  __shared__ int hist[512];
  __shared__ int gbase[512];
  const int tid = threadIdx.x;
  const int total = 2 * E;
  const int base0 = blockIdx.x * WCHUNK;
  if (base0 >= total) return;
  const int cnt = min(WCHUNK, total - base0);
  for (int i = tid; i < 512; i += 256) hist[i] = 0;
  __syncthreads();
  for (int k = tid; k < cnt; k += 256)
    atomicAdd(&hist[((unsigned)ei[base0 + k]) >> 7], 1);
  __syncthreads();
  for (int b = tid; b < NB; b += 256) {
    int h = hist[b];
    gbase[b] = h ? atomicAdd(&gcursor[b], h) : 0;
  }
  __syncthreads();
  for (int i = tid; i < 512; i += 256) hist[i] = 0;
  __syncthreads();
  for (int k = tid; k < cnt; k += 256) {
    int i = base0 + k;
    int v = ei[i];
    int other = (i < E) ? ei[i + E] : ei[i - E];
    int b = ((unsigned)v) >> 7;
    int r = atomicAdd(&hist[b], 1);
    bdata[gbase[b] + r] = (((unsigned)(v & 127)) << 16) | (unsigned)other;
  }
}

// per-bucket counting sort: bdata segment -> node-sorted u16 'other' + rowptr
__global__ __launch_bounds__(256) void bsort_kernel(const unsigned* __restrict__ bdata,
    const int* __restrict__ boffs, unsigned short* __restrict__ adj2,
    int* __restrict__ rowptr, int N, int E2) {
  __shared__ int hist[128];
  __shared__ int loff[129];
  __shared__ int cur[128];
  const int b = blockIdx.x;
  const int beg = boffs[b], end = boffs[b + 1];
  const int tid = threadIdx.x;
  if (tid < 128) hist[tid] = 0;
  __syncthreads();
  for (int p = beg + tid; p < end; p += 256)
    atomicAdd(&hist[bdata[p] >> 16], 1);
  __syncthreads();
  if (tid < 64) {
    int a0 = hist[tid], a1 = hist[tid + 64];
    int v0 = a0;
    #pragma unroll
    for (int off = 1; off < 64; off <<= 1) {
      int t = __shfl_up(v0, off, 64);
      if (tid >= off) v0 += t;
    }
    int tot0 = __shfl(v0, 63, 64);
    int v1 = a1;
    #pragma unroll
    for (int off = 1; off < 64; off <<= 1) {
      int t = __shfl_up(v1, off, 64);
      if (tid >= off) v1 += t;
    }
    loff[tid] = v0 - a0;
    loff[tid + 64] = tot0 + v1 - a1;
    cur[tid] = v0 - a0;
    cur[tid + 64] = tot0 + v1 - a1;
    int n0 = (b << 7) + tid;
    int n1 = n0 + 64;
    if (n0 < N) rowptr[n0] = beg + loff[tid];
    if (n1 < N) rowptr[n1] = beg + loff[tid + 64];
  }
  if (b == 0 && tid == 0) rowptr[N] = E2;
  __syncthreads();
  for (int p = beg + tid; p < end; p += 256) {
    unsigned e = bdata[p];
    int r = atomicAdd(&cur[e >> 16], 1);
    adj2[beg + r] = (unsigned short)(e & 0xFFFFu);
  }
}

// bf16 gather-aggregate, 4-way unrolled neighbor loop (4 gathers in flight).
__global__ __launch_bounds__(256) void aggb_s_kernel(const unsigned short* __restrict__ xb,
    const float* __restrict__ eps, const int* __restrict__ rowptr,
    const unsigned short* __restrict__ adj2, unsigned short* __restrict__ aggb, int N) {
  int n = blockIdx.x * 16 + (threadIdx.x >> 4);
  if (n >= N) return;
  int lane = threadIdx.x & 15;
  float s = 1.0f + eps[0];
  const unsigned short* lanebase = xb + (size_t)lane * 8;
  short8v own = *(const short8v*)(lanebase + ((size_t)n << 7));
  float accA[8], accB[8];
  #pragma unroll
  for (int j = 0; j < 8; ++j) { accA[j] = bf2f((unsigned short)own[j]) * s; accB[j] = 0.f; }
  int beg = rowptr[n], end = rowptr[n + 1];
  int p = beg;
  for (; p + 4 <= end; p += 4) {
    int j0 = adj2[p + 0];
    int j1 = adj2[p + 1];
    int j2 = adj2[p + 2];
    int j3 = adj2[p + 3];
    short8v v0 = *(const short8v*)(lanebase + ((size_t)j0 << 7));
    short8v v1 = *(const short8v*)(lanebase + ((size_t)j1 << 7));
    short8v v2 = *(const short8v*)(lanebase + ((size_t)j2 << 7));
    short8v v3 = *(const short8v*)(lanebase + ((size_t)j3 << 7));
    #pragma unroll
    for (int j = 0; j < 8; ++j) {
      accA[j] += bf2f((unsigned short)v0[j]) + bf2f((unsigned short)v2[j]);
      accB[j] += bf2f((unsigned short)v1[j]) + bf2f((unsigned short)v3[j]);
    }
  }
  for (; p < end; ++p) {
    int jn = adj2[p];
    short8v v = *(const short8v*)(lanebase + ((size_t)jn << 7));
    #pragma unroll
    for (int j = 0; j < 8; ++j) accA[j] += bf2f((unsigned short)v[j]);
  }
  short8v o;
  #pragma unroll
  for (int j = 0; j < 8; ++j) o[j] = (short)f2bf(accA[j] + accB[j]);
  *(short8v*)(aggb + ((size_t)n << 7) + lane * 8) = o;
}

// ================= legacy CSR kernels (tier2 fallback) =================

__global__ __launch_bounds__(256) void count_kernel(const int* __restrict__ ei,
                                                    int* __restrict__ deg, int total) {
  int i = blockIdx.x * blockDim.x + threadIdx.x;
  int stride = gridDim.x * blockDim.x;
  for (; i < total; i += stride) atomicAdd(&deg[ei[i]], 1);
}

__global__ __launch_bounds__(64) void scan_kernel(const int* __restrict__ deg,
                                                  int* __restrict__ rowptr, int n) {
  int lane = threadIdx.x;
  int carry = 0;
  if (lane == 0) rowptr[0] = 0;
  for (int base = 0; base < n; base += 64) {
    int i = base + lane;
    int v = (i < n) ? deg[i] : 0;
    #pragma unroll
    for (int off = 1; off < 64; off <<= 1) {
      int t = __shfl_up(v, off, 64);
      if (lane >= off) v += t;
    }
    int incl = v + carry;
    if (i < n) rowptr[i + 1] = incl;
    carry = __shfl(incl, 63, 64);
  }
}

__global__ __launch_bounds__(256) void chunk_reduce_kernel(const int* __restrict__ deg,
                                                           int* __restrict__ csum, int n) {
  __shared__ int wsum[4];
  int base = blockIdx.x * 1024;
  int tid = threadIdx.x;
  int s = 0;
  #pragma unroll
  for (int j = 0; j < 4; ++j) {
    int i = base + tid * 4 + j;
    if (i < n) s += deg[i];
  }
  #pragma unroll
  for (int off = 1; off < 64; off <<= 1) s += __shfl_xor(s, off, 64);
  if ((tid & 63) == 0) wsum[tid >> 6] = s;
  __syncthreads();
  if (tid == 0) csum[blockIdx.x] = wsum[0] + wsum[1] + wsum[2] + wsum[3];
}

__global__ __launch_bounds__(256) void chunk_scan_c_kernel(const int* __restrict__ deg,
    const int* __restrict__ coffs, int* __restrict__ rowptr,
    int* __restrict__ cursor, int n) {
  __shared__ int wpart[4];
  int b = blockIdx.x;
  int base = b * 1024;
  int tid = threadIdx.x;
  int lane = tid & 63, wv = tid >> 6;
  int v[4], s = 0;
  #pragma unroll
  for (int j = 0; j < 4; ++j) {
    int i = base + tid * 4 + j;
    v[j] = (i < n) ? deg[i] : 0;
    s += v[j];
  }
  int incl = s;
  #pragma unroll
  for (int off = 1; off < 64; off <<= 1) {
    int t = __shfl_up(incl, off, 64);
    if (lane >= off) incl += t;
  }
  if (lane == 63) wpart[wv] = incl;
  __syncthreads();
  int woff = 0;
  for (int k = 0; k < wv; ++k) woff += wpart[k];
  int run = incl - s + woff + coffs[b];
  #pragma unroll
  for (int j = 0; j < 4; ++j) {
    int i = base + tid * 4 + j;
    if (i < n) {
      cursor[i] = run;
      run += v[j];
      rowptr[i + 1] = run;
    }
  }
  if (b == 0 && tid == 0) rowptr[0] = 0;
}

__global__ __launch_bounds__(256) void fill_batch_kernel(const int* __restrict__ ei,
    int* __restrict__ cursor, int* __restrict__ adj, int E) {
  int total = 2 * E;
  int T = gridDim.x * blockDim.x;
  int t = blockIdx.x * blockDim.x + threadIdx.x;
  int vv[FILLK], oo[FILLK], pp[FILLK];
  for (long long base = 0; base < total; base += (long long)T * FILLK) {
    #pragma unroll
    for (int k = 0; k < FILLK; ++k) {
      long long i = base + (long long)k * T + t;
      if (i < total) {
        int ii = (int)i;
        vv[k] = ei[ii];
        oo[k] = (ii < E) ? ei[ii + E] : ei[ii - E];
      } else {
        vv[k] = -1; oo[k] = 0;
      }
    }
    #pragma unroll
    for (int k = 0; k < FILLK; ++k)
      pp[k] = (vv[k] >= 0) ? atomicAdd(&cursor[vv[k]], 1) : 0;
    #pragma unroll
    for (int k = 0; k < FILLK; ++k)
      if (vv[k] >= 0) adj[pp[k]] = oo[k];
  }
}

__global__ __launch_bounds__(256) void aggb_kernel(const unsigned short* __restrict__ xb,
    const float* __restrict__ eps, const int* __restrict__ rowptr,
    const int* __restrict__ adj, unsigned short* __restrict__ aggb, int N) {
  int n = blockIdx.x * 16 + (threadIdx.x >> 4);
  if (n >= N) return;
  int lane = threadIdx.x & 15;
  float s = 1.0f + eps[0];
  const unsigned short* base = xb + (size_t)n * 128 + lane * 8;
  short8v own = *(const short8v*)base;
  float acc[8];
  #pragma unroll
  for (int j = 0; j < 8; ++j) acc[j] = bf2f((unsigned short)own[j]) * s;
  int beg = rowptr[n], end = rowptr[n + 1];
  for (int p = beg; p < end; ++p) {
    int nb = adj[p];
    short8v v = *(const short8v*)(xb + (size_t)nb * 128 + lane * 8);
    #pragma unroll
    for (int j = 0; j < 8; ++j) acc[j] += bf2f((unsigned short)v[j]);
  }
  short8v o;
  #pragma unroll
  for (int j = 0; j < 8; ++j) o[j] = (short)f2bf(acc[j]);
  *(short8v*)(aggb + (size_t)n * 128 + lane * 8) = o;
}

// ---------------- tier0 ----------------

__global__ __launch_bounds__(256) void init_kernel(const float* __restrict__ x,
                                                   const float* __restrict__ eps,
                                                   float* __restrict__ agg, int total4) {
  float scale = 1.0f + eps[0];
  int idx = blockIdx.x * blockDim.x + threadIdx.x;
  int stride = gridDim.x * blockDim.x;
  const float4* x4 = (const float4*)x;
  float4* a4 = (float4*)agg;
  for (int i = idx; i < total4; i += stride) {
    float4 v = x4[i];
    v.x *= scale; v.y *= scale; v.z *= scale; v.w *= scale;
    a4[i] = v;
  }
}

__global__ __launch_bounds__(256) void scatter_kernel(const float* __restrict__ x,
    const int* __restrict__ src, const int* __restrict__ dst,
    float* __restrict__ agg, int E) {
  long long total = (long long)E * 32;
  long long idx = (long long)blockIdx.x * blockDim.x + threadIdx.x;
  long long stride = (long long)gridDim.x * blockDim.x;
  for (; idx < total; idx += stride) {
    int e = (int)(idx >> 5);
    int f4 = (int)(idx & 31);
    int s = src[e], d = dst[e];
    float4 xs = ((const float4*)x)[(size_t)s * 32 + f4];
    float4 xd = ((const float4*)x)[(size_t)d * 32 + f4];
    float* as = agg + (size_t)s * 128 + f4 * 4;
    float* ad = agg + (size_t)d * 128 + f4 * 4;
    atomicAdd(as + 0, xd.x); atomicAdd(as + 1, xd.y);
    atomicAdd(as + 2, xd.z); atomicAdd(as + 3, xd.w);
    atomicAdd(ad + 0, xs.x); atomicAdd(ad + 1, xs.y);
    atomicAdd(ad + 2, xs.z); atomicAdd(ad + 3, xs.w);
  }
}

// ---------------- MFMA MLP, bf16-agg input ----------------

__global__ __launch_bounds__(256) void mlp_mfma_b_kernel(
    const unsigned short* __restrict__ aggb, const short* __restrict__ w1p,
    const short* __restrict__ w2p, const float* __restrict__ b1,
    const float* __restrict__ b2, float* __restrict__ out, int N) {
  __shared__ short s_h[32 * 512];   // hmid bf16, XOR-swizzled, 32 KB
  const int tid = threadIdx.x;
  const int w = tid >> 6, l = tid & 63;
  const int l15 = l & 15, lg = l >> 4;
  const int brow = blockIdx.x * 32;

  short8v af[2][4];
  #pragma unroll
  for (int mt = 0; mt < 2; ++mt) {
    int row = brow + mt * 16 + l15;
    #pragma unroll
    for (int ks = 0; ks < 4; ++ks) {
      short8v s = (short8v)(short)0;
      if (row < N)
        s = *(const short8v*)(aggb + (size_t)row * 128 + ks * 32 + lg * 8);
      af[mt][ks] = s;
    }
  }

  f32x4 acc1[2][8];
  #pragma unroll
  for (int nt = 0; nt < 8; ++nt) {
    float bv = b1[(w * 8 + nt) * 16 + l15];
    acc1[0][nt] = (f32x4){bv, bv, bv, bv};
    acc1[1][nt] = (f32x4){bv, bv, bv, bv};
  }
  #pragma unroll
  for (int nt = 0; nt < 8; ++nt) {
    int ntg = w * 8 + nt;
    #pragma unroll
    for (int ks = 0; ks < 4; ++ks) {
      short8v bf = *(const short8v*)(w1p + ((ntg * 4 + ks) << 9) + l * 8);
      acc1[0][nt] = __builtin_amdgcn_mfma_f32_16x16x32_bf16(af[0][ks], bf, acc1[0][nt], 0, 0, 0);
      acc1[1][nt] = __builtin_amdgcn_mfma_f32_16x16x32_bf16(af[1][ks], bf, acc1[1][nt], 0, 0, 0);
    }
  }

  #pragma unroll
  for (int mt = 0; mt < 2; ++mt)
    #pragma unroll
    for (int nt = 0; nt < 8; ++nt) {
      int col = (w * 8 + nt) * 16 + l15;
      #pragma unroll
      for (int reg = 0; reg < 4; ++reg) {
        int row = mt * 16 + lg * 4 + reg;
        float v = fmaxf(acc1[mt][nt][reg], 0.f);
        int byte = (row << 10) + (col << 1);
        byte ^= (row & 7) << 4;
        *(short*)((char*)s_h + byte) = (short)f2bf(v);
      }
    }
  __syncthreads();

  f32x4 acc2[2][2];
  #pragma unroll
  for (int ntl = 0; ntl < 2; ++ntl) {
    float bv = b2[(w * 2 + ntl) * 16 + l15];
    acc2[0][ntl] = (f32x4){bv, bv, bv, bv};
    acc2[1][ntl] = (f32x4){bv, bv, bv, bv};
  }
  #pragma unroll
  for (int ks = 0; ks < 16; ++ks) {
    short8v a2[2];
    #pragma unroll
    for (int mt = 0; mt < 2; ++mt) {
      int row = mt * 16 + l15;
      int byte = (row << 10) + ((ks * 32 + lg * 8) << 1);
      byte ^= (row & 7) << 4;
      a2[mt] = *(short8v*)((char*)s_h + byte);
    }
    #pragma unroll
    for (int ntl = 0; ntl < 2; ++ntl) {
      int ntg = w * 2 + ntl;
      short8v bf = *(const short8v*)(w2p + ((ntg * 16 + ks) << 9) + l * 8);
      acc2[0][ntl] = __builtin_amdgcn_mfma_f32_16x16x32_bf16(a2[0], bf, acc2[0][ntl], 0, 0, 0);
      acc2[1][ntl] = __builtin_amdgcn_mfma_f32_16x16x32_bf16(a2[1], bf, acc2[1][ntl], 0, 0, 0);
    }
  }

  #pragma unroll
  for (int mt = 0; mt < 2; ++mt)
    #pragma unroll
    for (int ntl = 0; ntl < 2; ++ntl)
      #pragma unroll
      for (int reg = 0; reg < 4; ++reg) {
        int row = brow + mt * 16 + lg * 4 + reg;
        if (row < N)
          out[(size_t)row * 128 + (w * 2 + ntl) * 16 + l15] = acc2[mt][ntl][reg];
      }
}

// ---------------- fallback SIMT MLP (tier0) ----------------

__global__ __launch_bounds__(256) void mlp_kernel(
    const float* agg, const float* __restrict__ W1,
    const float* __restrict__ b1, const float* __restrict__ W2,
    const float* __restrict__ b2, float* out, int N) {
  __shared__ float s_agg[MROWS][128];
  __shared__ float s_h[MROWS][65];
  const int tid = threadIdx.x;
  const int block_row = blockIdx.x * MROWS;

  for (int i = tid; i < MROWS * 32; i += 256) {
    int r = i >> 5, c4 = i & 31;
    if (block_row + r < N)
      ((float4*)&s_agg[r][0])[c4] = ((const float4*)agg)[(size_t)(block_row + r) * 32 + c4];
    else
      ((float4*)&s_agg[r][0])[c4] = make_float4(0.f, 0.f, 0.f, 0.f);
  }
  __syncthreads();

  const int r = tid >> 3;
  const int f0 = (tid & 7) << 4;
  float acc[16];
  #pragma unroll
  for (int j = 0; j < 16; ++j) acc[j] = b2[f0 + j];

  const int hc = tid & 63;
  const int hr0 = tid >> 6;

  for (int h0 = 0; h0 < 512; h0 += 64) {
    float sum[8];
    float bv = b1[h0 + hc];
    #pragma unroll
    for (int j = 0; j < 8; ++j) sum[j] = bv;
    const float* w1col = W1 + h0 + hc;
    #pragma unroll 4
    for (int k = 0; k < 128; ++k) {
      float wv = w1col[(size_t)k * 512];
      #pragma unroll
      for (int j = 0; j < 8; ++j) sum[j] += s_agg[hr0 + (j << 2)][k] * wv;
    }
    __syncthreads();
    #pragma unroll
    for (int j = 0; j < 8; ++j) s_h[hr0 + (j << 2)][hc] = fmaxf(sum[j], 0.f);
    __syncthreads();

    for (int hcc = 0; hcc < 64; ++hcc) {
      float hv = s_h[r][hcc];
      const float4* w2p = (const float4*)(W2 + (size_t)(h0 + hcc) * 128 + f0);
      float4 w0 = w2p[0], w1v = w2p[1], w2v = w2p[2], w3v = w2p[3];
      acc[0]  += hv * w0.x;  acc[1]  += hv * w0.y;  acc[2]  += hv * w0.z;  acc[3]  += hv * w0.w;
      acc[4]  += hv * w1v.x; acc[5]  += hv * w1v.y; acc[6]  += hv * w1v.z; acc[7]  += hv * w1v.w;
      acc[8]  += hv * w2v.x; acc[9]  += hv * w2v.y; acc[10] += hv * w2v.z; acc[11] += hv * w2v.w;
      acc[12] += hv * w3v.x; acc[13] += hv * w3v.y; acc[14] += hv * w3v.z; acc[15] += hv * w3v.w;
    }
  }

  if (block_row + r < N) {
    float4* op = (float4*)(out + (size_t)(block_row + r) * 128 + f0);
    op[0] = make_float4(acc[0],  acc[1],  acc[2],  acc[3]);
    op[1] = make_float4(acc[4],  acc[5],  acc[6],  acc[7]);
    op[2] = make_float4(acc[8],  acc[9],  acc[10], acc[11]);
    op[3] = make_float4(acc[12], acc[13], acc[14], acc[15]);
  }
}

extern "C" void kernel_launch(void* const* d_in, const int* in_sizes, int n_in,
                              void* d_out, int out_size, void* d_ws, size_t ws_size,
                              hipStream_t stream) {
  const float* x   = (const float*)d_in[0];
  const int*   ei  = (const int*)d_in[1];
  const float* eps = (const float*)d_in[2];
  const float* W1  = (const float*)d_in[3];
  const float* b1  = (const float*)d_in[4];
  const float* W2  = (const float*)d_in[5];
  const float* b2  = (const float*)d_in[6];
  float* out = (float*)d_out;

  const int N = in_sizes[0] / 128;
  const int E = in_sizes[1] / 2;
  const int nChunks = (N + 1023) / 1024;
  const int NB = (N + 127) >> 7;
  int mblocks = (N + MROWS - 1) / MROWS;

  size_t wp_bytes = 2u * 65536u * sizeof(short);
  size_t xb_bytes = ((size_t)N * 128 * sizeof(short) + 15) & ~(size_t)15;

  // bucket+sort layout: bcount(NB) | gcursor(NB) | boffs(NB+1) | rowptr(N+1) |
  //                     bdata(2E u32) | adj2(2E u16 = E+1 ints) | w | xb | aggb
  size_t bt_ints = (size_t)2 * NB + (NB + 1) + (size_t)(N + 1) + (size_t)2 * E + (size_t)(E + 1);
  size_t bt_al = ((bt_ints * sizeof(int)) + 15) & ~(size_t)15;
  size_t need_bt = bt_al + wp_bytes + 2 * xb_bytes;

  // tier2 layout: deg(N) | cursor(N) | rowptr(N+1) | adj(2E) | csum | coffs | w | xb | aggb
  size_t csr_ints = (size_t)(3 * N + 1 + 2 * E) + (size_t)(2 * nChunks + 1);
  size_t csr_al = ((csr_ints * sizeof(int)) + 15) & ~(size_t)15;
  size_t need_t1 = csr_al + wp_bytes;
  size_t need_t2 = need_t1 + 2 * xb_bytes;

  if (N <= 65536 && ws_size >= need_bt) {
    // ---- bucket+sort tier ----
    int* bcount  = (int*)d_ws;
    int* gcursor = bcount + NB;
    int* boffs   = gcursor + NB;                     // NB+1
    int* rowptr  = boffs + NB + 1;                   // N+1
    unsigned* bdata = (unsigned*)(rowptr + N + 1);   // 2E
    unsigned short* adj2 = (unsigned short*)(bdata + 2 * E);  // 2E u16
    short* w1p  = (short*)((char*)d_ws + bt_al);
    short* w2p  = w1p + 65536;
    unsigned short* xb   = (unsigned short*)((char*)d_ws + bt_al + wp_bytes);
    unsigned short* aggb = (unsigned short*)((char*)d_ws + bt_al + wp_bytes + xb_bytes);

    prep_kernel<<<2048, 256, 0, stream>>>(x, W1, W2, bcount, xb, w1p, w2p, N, NB);
    bcount_kernel<<<256, 256, 0, stream>>>(ei, bcount, 2 * E, NB);
    scan_cur_kernel<<<1, 64, 0, stream>>>(bcount, boffs, gcursor, NB);
    int wblocks = (2 * E + WCHUNK - 1) / WCHUNK;
    bwrite_kernel<<<wblocks, 256, 0, stream>>>(ei, gcursor, bdata, E, NB);
    bsort_kernel<<<NB, 256, 0, stream>>>(bdata, boffs, adj2, rowptr, N, 2 * E);
    aggb_s_kernel<<<(N + 15) / 16, 256, 0, stream>>>(xb, eps, rowptr, adj2, aggb, N);
    mlp_mfma_b_kernel<<<mblocks, 256, 0, stream>>>(aggb, w1p, w2p, b1, b2, out, N);
  } else if (ws_size >= need_t2) {
    // ---- tier2 (R8): batched atomic fill + bf16 gather + MFMA MLP ----
    int* deg    = (int*)d_ws;
    int* cursor = deg + N;
    int* rowptr = cursor + N;
    int* adj    = rowptr + (N + 1);
    int* csum   = adj + 2 * E;
    int* coffs  = csum + nChunks;
    short* w1p  = (short*)((char*)d_ws + csr_al);
    short* w2p  = w1p + 65536;
    unsigned short* xb   = (unsigned short*)((char*)d_ws + need_t1);
    unsigned short* aggb = (unsigned short*)((char*)d_ws + need_t1 + xb_bytes);

    prep_kernel<<<2048, 256, 0, stream>>>(x, W1, W2, deg, xb, w1p, w2p, N, 2 * N);
    count_kernel<<<4096, 256, 0, stream>>>(ei, deg, 2 * E);
    chunk_reduce_kernel<<<nChunks, 256, 0, stream>>>(deg, csum, N);
    scan_kernel<<<1, 64, 0, stream>>>(csum, coffs, nChunks);
    chunk_scan_c_kernel<<<nChunks, 256, 0, stream>>>(deg, coffs, rowptr, cursor, N);
    int fblocks = (2 * E + 256 * FILLK - 1) / (256 * FILLK);
    fill_batch_kernel<<<fblocks, 256, 0, stream>>>(ei, cursor, adj, E);
    aggb_kernel<<<(N + 15) / 16, 256, 0, stream>>>(xb, eps, rowptr, adj, aggb, N);
    mlp_mfma_b_kernel<<<mblocks, 256, 0, stream>>>(aggb, w1p, w2p, b1, b2, out, N);
  } else {
    // ---- tier0 ----
    init_kernel<<<2048, 256, 0, stream>>>(x, eps, out, N * 32);
    scatter_kernel<<<4096, 256, 0, stream>>>(x, ei, ei + E, out, E);
    mlp_kernel<<<mblocks, 256, 0, stream>>>(out, W1, b1, W2, b2, out, N);
  }
}